// Round 11
// baseline (1184.886 us; speedup 1.0000x reference)
//
#include <hip/hip_runtime.h>
#include <math.h>

#define NTOK   131040   // 8*91*180
#define NTOKW  138240   // 15*64*144

typedef __attribute__((ext_vector_type(8))) short bf16x8;
typedef __attribute__((ext_vector_type(8))) unsigned short u16x8;
typedef __attribute__((ext_vector_type(4))) float f32x4;
typedef __attribute__((ext_vector_type(2))) float f32x2;

__device__ __forceinline__ float b2f(unsigned short u){
  union { unsigned u; float f; } v; v.u = ((unsigned)u) << 16; return v.f;
}
__device__ __forceinline__ unsigned short f2b(float f){
  union { float f; unsigned u; } v; v.f = f;
  unsigned r = v.u + 0x7FFFu + ((v.u >> 16) & 1u);
  return (unsigned short)(r >> 16);
}
// tanh-GELU via rcpf (no f32 div sequence); |err vs erf-GELU| ~3e-4
__device__ __forceinline__ float gelu_fast(float x){
  float t = 0.79788456080286536f * (x + 0.044715f * x * x * x);
  float e = __expf(2.0f * t);
  float th = 1.0f - 2.0f * __builtin_amdgcn_rcpf(e + 1.0f);
  return 0.5f * x * (1.0f + th);
}
__device__ __forceinline__ unsigned pk_bf16(float lo, float hi){
  unsigned r;
  asm("v_cvt_pk_bf16_f32 %0, %1, %2" : "=v"(r) : "v"(lo), "v"(hi));
  return r;
}
__device__ __forceinline__ void lds_barrier(){
  asm volatile("s_waitcnt lgkmcnt(0)" ::: "memory");
  __builtin_amdgcn_sched_barrier(0);
  __builtin_amdgcn_s_barrier();
  __builtin_amdgcn_sched_barrier(0);
}

// transpose-cast: dst[n][k] = (bf16)src[k][n]
__global__ __launch_bounds__(256) void transp(const float* __restrict__ src,
                                              unsigned short* __restrict__ dst,
                                              int K, int N){
  int i = blockIdx.x*256 + threadIdx.x;
  if (i < K*N){
    int n = i / K, k = i % K;
    dst[i] = f2b(src[(size_t)k*N + n]);
  }
}

// precompute bias+mask in MFMA-fragment layout:
// bw[(((slice*9 + wv)*5 + vec)*64 + lane)*8 + elem], e = vec*8+elem = ct*4+r (<36)
// i = wv*16 + (lane>>4)*4 + r ; j = ct*16 + (lane&15) ; slice = tw*6+head
__global__ __launch_bounds__(256) void bias_pre(
    const float* __restrict__ btab,
    unsigned short* __restrict__ bw,
    int roll)
{
  int gid = blockIdx.x*256 + threadIdx.x;   // < 384*9*64*40
  int e    = gid % 40;
  int rem  = gid / 40;
  int lane = rem % 64;
  int rem2 = rem / 64;
  int wv   = rem2 % 9;
  int slice= rem2 / 9;
  unsigned short out = 0;
  if (e < 36){
    int ct = e >> 2, r = e & 3;
    int i = wv*16 + (lane>>4)*4 + r;
    int j = ct*16 + (lane & 15);
    int tw = slice / 6, head = slice % 6;
    int ia = i/72, ib = (i%72)/12, ic = i%12;
    int ja = j/72, jb = (j%72)/12, jc = j%12;
    int idx = (ia + 2*ja)*828 + (ib + 6*jb)*23 + (ic - jc + 11);
    float v = btab[(size_t)idx*384 + tw*6 + head];
    if (roll){
      int nz = tw >> 4, nh = tw & 15;
      int zi = nz*2+ia, hi = nh*6+ib, zj = nz*2+ja, hj = nh*6+jb;
      int ri = 3*((zi<6)?0:((zi<7)?1:2)) + ((hi<90)?0:((hi<93)?1:2));
      int rj = 3*((zj<6)?0:((zj<7)?1:2)) + ((hj<90)?0:((hj<93)?1:2));
      if (ri != rj) v -= 100.0f;
    }
    out = f2b(v);
  }
  // layout: e is fastest within (vec,elem): gid enumerates exactly the store order
  // bw index = ((slice*9+wv)*64 + lane)*40 + e  ==  rearranged below
  // we want [slice][wv][vec][lane][elem]; remap:
  int vec = e >> 3, elem = e & 7;
  size_t di = ((((size_t)slice*9 + wv)*5 + vec)*64 + lane)*8 + elem;
  bw[di] = out;
}

// window-partition gather (+pad +roll), fp32 -> bf16
__global__ __launch_bounds__(256) void gather_win(const float* __restrict__ x,
                                                  unsigned short* __restrict__ xw,
                                                  int roll){
  int gid = blockIdx.x*256 + threadIdx.x;
  int row = gid / 24;
  int dp  = gid % 24;
  int tok = row % 144;
  int wt  = row / 144;
  int tw  = wt & 63;
  int w   = wt >> 6;
  int nz = tw >> 4, nh = tw & 15;
  int wz = tok / 72; int rem = tok % 72; int wh = rem / 12; int ww = rem % 12;
  int z = nz*2 + wz, h = nh*6 + wh, wc = w*12 + ww;
  if (roll){ z = (z+1)&7; h = (h+3)%96; wc = (wc+6)%180; }
  int d0 = dp*8;
  u16x8 o;
  if (h < 91){
    const float* s = x + ((size_t)((z*91 + h)*180 + wc))*192 + d0;
    #pragma unroll
    for (int i=0;i<8;i++) o[i] = f2b(s[i]);
  } else {
    #pragma unroll
    for (int i=0;i<8;i++) o[i] = 0;
  }
  *(u16x8*)(xw + (size_t)row*192 + d0) = o;
}

// K=192 GEMM: C[M x N] = A[M x 192] @ Bt[N x 192]^T + bias
__global__ __launch_bounds__(512) void gemm_k192(
    const unsigned short* __restrict__ A,
    const unsigned short* __restrict__ Bt,
    const float* __restrict__ bias,
    unsigned short* __restrict__ C,
    int N)
{
  __shared__ unsigned short Bst[192][200];
  int m0 = blockIdx.x * 128;
  int n0 = blockIdx.y * 192;
  int t = threadIdx.x;
  int lane = t & 63, w = t >> 6;
  int wm = w >> 2, wn = w & 3;
  int lg = lane >> 4, lr = lane & 15;

  #pragma unroll
  for (int i=0;i<9;i++){
    int idx = t + i*512;
    int r = idx / 24, c = (idx % 24)*8;
    *(u16x8*)&Bst[r][c] = *(const u16x8*)(Bt + (size_t)(n0 + r)*192 + c);
  }
  __syncthreads();

  const unsigned short* aRow = A + (size_t)(m0 + wm*64 + lr)*192 + lg*8;

  f32x4 acc[4][3];
  #pragma unroll
  for (int a=0;a<4;a++)
    #pragma unroll
    for (int b=0;b<3;b++) acc[a][b] = (f32x4){0.f,0.f,0.f,0.f};

  bf16x8 aP[2][6];
  #pragma unroll
  for (int ks=0; ks<6; ks++) aP[0][ks] = *(const bf16x8*)(aRow + ks*32);

  #pragma unroll
  for (int rt=0; rt<4; rt++){
    if (rt < 3){
      const unsigned short* an = aRow + (size_t)(rt+1)*16*192;
      #pragma unroll
      for (int ks=0; ks<6; ks++) aP[(rt+1)&1][ks] = *(const bf16x8*)(an + ks*32);
    }
    #pragma unroll
    for (int ks=0; ks<6; ks++){
      bf16x8 b0 = *(const bf16x8*)&Bst[wn*48 +      lr][ks*32 + lg*8];
      bf16x8 b1 = *(const bf16x8*)&Bst[wn*48 + 16 + lr][ks*32 + lg*8];
      bf16x8 b2 = *(const bf16x8*)&Bst[wn*48 + 32 + lr][ks*32 + lg*8];
      bf16x8 af = aP[rt&1][ks];
      acc[rt][0] = __builtin_amdgcn_mfma_f32_16x16x32_bf16(af, b0, acc[rt][0], 0,0,0);
      acc[rt][1] = __builtin_amdgcn_mfma_f32_16x16x32_bf16(af, b1, acc[rt][1], 0,0,0);
      acc[rt][2] = __builtin_amdgcn_mfma_f32_16x16x32_bf16(af, b2, acc[rt][2], 0,0,0);
    }
  }

  #pragma unroll
  for (int rt=0; rt<4; rt++){
    #pragma unroll
    for (int fn=0; fn<3; fn++){
      int colg = n0 + wn*48 + fn*16 + lr;
      float bv = bias[colg];
      #pragma unroll
      for (int r=0;r<4;r++){
        int rowg = m0 + wm*64 + rt*16 + lg*4 + r;
        C[(size_t)rowg*N + colg] = f2b(acc[rt][fn][r] + bv);
      }
    }
  }
}

// fused windowed attention: one block per (window-pair, head). 9 waves.
// bias via fragment-layout table: 5 coalesced u16x8 loads per lane.
__global__ __launch_bounds__(576) void attn_win(
    const unsigned short* __restrict__ qkv,
    const unsigned short* __restrict__ bw,
    unsigned short* __restrict__ outp)
{
  __shared__ union {
    struct { unsigned short Qs[144][32]; unsigned short Ks[144][40]; } qk;
    unsigned short Ps[144][160];
  } U;
  __shared__ unsigned short Vst[32][160];

  int b = blockIdx.x;
  int head = b % 6;
  int wt = b / 6;
  int tw = wt & 63;
  int t = threadIdx.x;
  int lane = t & 63;
  int wv = t >> 6;
  int lg = lane >> 4, lr = lane & 15;

  {
    int tok = t >> 2, c0 = (t & 3)*8;
    size_t base = ((size_t)wt*144 + tok)*576 + head*32 + c0;
    u16x8 qv = *(const u16x8*)(qkv + base);
    u16x8 kv = *(const u16x8*)(qkv + base + 192);
    u16x8 vv = *(const u16x8*)(qkv + base + 384);
    u16x8 qs;
    #pragma unroll
    for (int i=0;i<8;i++) qs[i] = f2b(b2f(qv[i]) * 0.17677669529663687f);
    *(u16x8*)&U.qk.Qs[tok][c0] = qs;
    *(u16x8*)&U.qk.Ks[tok][c0] = kv;
    #pragma unroll
    for (int i=0;i<8;i++) Vst[c0+i][tok] = vv[i];
  }
  if (t < 512) Vst[t >> 4][144 + (t & 15)] = 0;

  // issue bias fragment loads early (independent of LDS)
  u16x8 bv0, bv1, bv2, bv3, bv4;
  {
    size_t sbase = ((((size_t)(tw*6 + head))*9 + wv)*5*64 + lane)*8;
    bv0 = *(const u16x8*)(bw + sbase);
    bv1 = *(const u16x8*)(bw + sbase + 64*8);
    bv2 = *(const u16x8*)(bw + sbase + 2*64*8);
    bv3 = *(const u16x8*)(bw + sbase + 3*64*8);
    bv4 = *(const u16x8*)(bw + sbase + 4*64*8);
  }
  __syncthreads();

  float s[9][4];
  {
    bf16x8 a = *(const bf16x8*)&U.qk.Qs[wv*16 + lr][lg*8];
    #pragma unroll
    for (int ct=0; ct<9; ct++){
      bf16x8 bb = *(const bf16x8*)&U.qk.Ks[ct*16 + lr][lg*8];
      f32x4 d = {0.f,0.f,0.f,0.f};
      d = __builtin_amdgcn_mfma_f32_16x16x32_bf16(a, bb, d, 0,0,0);
      s[ct][0]=d[0]; s[ct][1]=d[1]; s[ct][2]=d[2]; s[ct][3]=d[3];
    }
  }

  // add bias from fragment registers (e = ct*4+r; constant indices after unroll)
  #pragma unroll
  for (int ct=0; ct<9; ct++){
    #pragma unroll
    for (int r=0;r<4;r++){
      const int e = ct*4 + r;
      unsigned short bu =
        (e < 8)  ? bv0[e & 7] :
        (e < 16) ? bv1[e & 7] :
        (e < 24) ? bv2[e & 7] :
        (e < 32) ? bv3[e & 7] : bv4[e & 7];
      s[ct][r] += b2f(bu);
    }
  }

  float mx[4] = {-1e30f,-1e30f,-1e30f,-1e30f};
  #pragma unroll
  for (int ct=0; ct<9; ct++)
    #pragma unroll
    for (int r=0;r<4;r++) mx[r] = fmaxf(mx[r], s[ct][r]);
  #pragma unroll
  for (int off=1; off<16; off<<=1)
    #pragma unroll
    for (int r=0;r<4;r++) mx[r] = fmaxf(mx[r], __shfl_xor(mx[r], off));
  float sm[4] = {0.f,0.f,0.f,0.f};
  #pragma unroll
  for (int ct=0; ct<9; ct++)
    #pragma unroll
    for (int r=0;r<4;r++){ s[ct][r] = __expf(s[ct][r] - mx[r]); sm[r] += s[ct][r]; }
  #pragma unroll
  for (int off=1; off<16; off<<=1)
    #pragma unroll
    for (int r=0;r<4;r++) sm[r] += __shfl_xor(sm[r], off);
  float inv[4];
  #pragma unroll
  for (int r=0;r<4;r++) inv[r] = 1.0f / sm[r];

  lds_barrier();

  #pragma unroll
  for (int ct=0; ct<9; ct++)
    #pragma unroll
    for (int r=0;r<4;r++)
      U.Ps[wv*16 + lg*4 + r][ct*16 + lr] = f2b(s[ct][r] * inv[r]);
  #pragma unroll
  for (int r=0;r<4;r++) U.Ps[wv*16 + lg*4 + r][144 + lr] = 0;
  __syncthreads();

  #pragma unroll
  for (int ct2=0; ct2<2; ct2++){
    f32x4 o = {0.f,0.f,0.f,0.f};
    #pragma unroll
    for (int kt=0; kt<5; kt++){
      bf16x8 a  = *(const bf16x8*)&U.Ps[wv*16 + lr][kt*32 + lg*8];
      bf16x8 bb = *(const bf16x8*)&Vst[ct2*16 + lr][kt*32 + lg*8];
      o = __builtin_amdgcn_mfma_f32_16x16x32_bf16(a, bb, o, 0,0,0);
    }
    size_t rb = ((size_t)wt*144 + wv*16 + lg*4)*192 + head*32 + ct2*16 + lr;
    #pragma unroll
    for (int r=0;r<4;r++) outp[rb + (size_t)r*192] = f2b(o[r]);
  }
}

// un-window (+unroll +crop) + LN + residual
__global__ __launch_bounds__(256) void unwin_ln(
  const unsigned short* __restrict__ ywin,
  const float* __restrict__ xsrc,
  const float* __restrict__ g, const float* __restrict__ bb,
  float* __restrict__ outf, unsigned short* __restrict__ outb, int roll)
{
  int tok = blockIdx.x*4 + (threadIdx.x>>6);
  if (tok >= NTOK) return;
  int lane = threadIdx.x & 63;
  int z = tok / (91*180);
  int rem = tok % (91*180);
  int h = rem / 180, wc = rem % 180;
  int zz=z, hh=h, ww=wc;
  if (roll){ zz = (z+7)&7; hh = (h+93)%96; ww = (wc+174)%180; }
  int nz = zz>>1, wz = zz&1;
  int nh = hh/6,  wh = hh%6;
  int nw = ww/12, w2 = ww%12;
  size_t row = ((size_t)(nw*64 + nz*16 + nh))*144 + wz*72 + wh*12 + w2;
  const unsigned short* yr = ywin + row*192;
  float v[3]; float s=0.f, ss=0.f;
  #pragma unroll
  for (int i=0;i<3;i++){ v[i] = b2f(yr[lane + i*64]); s += v[i]; ss += v[i]*v[i]; }
  #pragma unroll
  for (int off=32; off>=1; off>>=1){ s += __shfl_xor(s, off); ss += __shfl_xor(ss, off); }
  float mean = s * (1.0f/192.0f);
  float var = ss * (1.0f/192.0f) - mean*mean;
  float rinv = rsqrtf(var + 1e-5f);
  size_t tb = (size_t)tok*192;
  #pragma unroll
  for (int i=0;i<3;i++){
    int d = lane + i*64;
    float o = xsrc[tb + d] + ((v[i]-mean)*rinv*g[d] + bb[d]);
    outf[tb+d] = o;
    outb[tb+d] = f2b(o);
  }
}

// fused MLP + final LN + residual: out = xmid + LN( gelu(A@W1+b1) @ W2 + b2 )
// 128 rows/block, 4 waves x 32 rows, single-buffered, reg-prefetch, LDS-only barriers.
__global__ __launch_bounds__(256) void mlp_fused_ln(
    const unsigned short* __restrict__ A,    // [M][192] bf16
    const unsigned short* __restrict__ W1t,  // [768][192]
    const float* __restrict__ bias1,         // [768]
    const unsigned short* __restrict__ W2t,  // [192][768]
    const float* __restrict__ mbias2,        // [192]
    const float* __restrict__ xmid,          // [M][192] f32
    const float* __restrict__ lng,           // [192]
    const float* __restrict__ lnb,           // [192]
    float* __restrict__ outF,                // [M][192] f32
    int M)
{
  __shared__ unsigned short W1s[32][204];   // stride 204: lr-lanes hit 16 distinct banks
  __shared__ unsigned short W2s[192][44];
  __shared__ unsigned short Hs[4][32][40];
  __shared__ float b1s[768];
  __shared__ float eps[576];                // [mb2 | lng | lnb]
  int m0 = blockIdx.x*128;
  int t = threadIdx.x, lane = t & 63, w = t >> 6;
  int lg = lane >> 4, lr = lane & 15;

  bf16x8 afrA[6], afrB[6];
  {
    int ra = m0 + w*32 + lr, rb = ra + 16;
    if (ra < M){
      const unsigned short* ap = A + (size_t)ra*192 + lg*8;
      #pragma unroll
      for (int ks=0; ks<6; ks++) afrA[ks] = *(const bf16x8*)(ap + ks*32);
    } else {
      #pragma unroll
      for (int ks=0; ks<6; ks++)
        #pragma unroll
        for (int j=0;j<8;j++) afrA[ks][j] = 0;
    }
    if (rb < M){
      const unsigned short* ap = A + (size_t)rb*192 + lg*8;
      #pragma unroll
      for (int ks=0; ks<6; ks++) afrB[ks] = *(const bf16x8*)(ap + ks*32);
    } else {
      #pragma unroll
      for (int ks=0; ks<6; ks++)
        #pragma unroll
        for (int j=0;j<8;j++) afrB[ks][j] = 0;
    }
  }

  b1s[t] = bias1[t];
  b1s[t + 256] = bias1[t + 256];
  b1s[t + 512] = bias1[t + 512];
  if (t < 192){ eps[t] = mbias2[t]; eps[192 + t] = lng[t]; eps[384 + t] = lnb[t]; }

  int i1r[3], i1c[3], i2r[3], i2c[3];
  #pragma unroll
  for (int i=0;i<3;i++){
    int idx = t + i*256;
    i1r[i] = idx/24; i1c[i] = (idx%24)*8;
    i2r[i] = idx/4;  i2c[i] = (idx&3)*8;
  }

  u16x8 w1r[3], w2r[3];
  #pragma unroll
  for (int i=0;i<3;i++){
    w1r[i] = *(const u16x8*)(W1t + (size_t)i1r[i]*192 + i1c[i]);
    w2r[i] = *(const u16x8*)(W2t + (size_t)i2r[i]*768 + i2c[i]);
  }

  f32x4 accA[12], accB[12];
  #pragma unroll
  for (int i=0;i<12;i++){ accA[i] = (f32x4){0.f,0.f,0.f,0.f}; accB[i] = (f32x4){0.f,0.f,0.f,0.f}; }

  for (int it=0; it<24; ++it){
    int hc = it*32;
    #pragma unroll
    for (int i=0;i<3;i++){
      *(u16x8*)&W1s[i1r[i]][i1c[i]] = w1r[i];
      *(u16x8*)&W2s[i2r[i]][i2c[i]] = w2r[i];
    }
    if (it < 23){
      int hc2 = hc + 32;
      #pragma unroll
      for (int i=0;i<3;i++){
        w1r[i] = *(const u16x8*)(W1t + (size_t)(hc2 + i1r[i])*192 + i1c[i]);
        w2r[i] = *(const u16x8*)(W2t + (size_t)i2r[i]*768 + hc2 + i2c[i]);
      }
    }
    lds_barrier();

    f32x4 h0a = (f32x4){0.f,0.f,0.f,0.f}, h1a = h0a, h0b = h0a, h1b = h0a;
    #pragma unroll
    for (int ks=0; ks<6; ks++){
      bf16x8 b0  = *(const bf16x8*)&W1s[2*lr    ][ks*32 + lg*8];
      bf16x8 b1f = *(const bf16x8*)&W1s[2*lr + 1][ks*32 + lg*8];
      h0a = __builtin_amdgcn_mfma_f32_16x16x32_bf16(afrA[ks], b0,  h0a, 0,0,0);
      h1a = __builtin_amdgcn_mfma_f32_16x16x32_bf16(afrA[ks], b1f, h1a, 0,0,0);
      h0b = __builtin_amdgcn_mfma_f32_16x16x32_bf16(afrB[ks], b0,  h0b, 0,0,0);
      h1b = __builtin_amdgcn_mfma_f32_16x16x32_bf16(afrB[ks], b1f, h1b, 0,0,0);
    }
    float bb0 = b1s[hc + 2*lr];
    float bb1 = b1s[hc + 2*lr + 1];
    #pragma unroll
    for (int r=0;r<4;r++){
      *(unsigned*)&Hs[w][lg*4 + r][2*lr] =
          pk_bf16(gelu_fast(h0a[r] + bb0), gelu_fast(h1a[r] + bb1));
      *(unsigned*)&Hs[w][16 + lg*4 + r][2*lr] =
          pk_bf16(gelu_fast(h0b[r] + bb0), gelu_fast(h1b[r] + bb1));
    }
    bf16x8 paA = *(const bf16x8*)&Hs[w][lr][lg*8];
    bf16x8 paB = *(const bf16x8*)&Hs[w][16 + lr][lg*8];
    #pragma unroll
    for (int f=0; f<6; f++){
      bf16x8 c0 = *(const bf16x8*)&W2s[f*32 + 2*lr    ][lg*8];
      bf16x8 c1 = *(const bf16x8*)&W2s[f*32 + 2*lr + 1][lg*8];
      accA[2*f]   = __builtin_amdgcn_mfma_f32_16x16x32_bf16(paA, c0, accA[2*f],   0,0,0);
      accA[2*f+1] = __builtin_amdgcn_mfma_f32_16x16x32_bf16(paA, c1, accA[2*f+1], 0,0,0);
      accB[2*f]   = __builtin_amdgcn_mfma_f32_16x16x32_bf16(paB, c0, accB[2*f],   0,0,0);
      accB[2*f+1] = __builtin_amdgcn_mfma_f32_16x16x32_bf16(paB, c1, accB[2*f+1], 0,0,0);
    }
    lds_barrier();
  }

  #pragma unroll
  for (int gsel=0; gsel<2; gsel++){
    f32x4* acc = gsel ? accB : accA;
    #pragma unroll
    for (int r=0;r<4;r++){
      int row = m0 + w*32 + gsel*16 + lg*4 + r;
      float s = 0.f, ss = 0.f;
      #pragma unroll
      for (int f=0; f<6; f++){
        float v0 = acc[2*f][r]   + eps[f*32 + 2*lr];
        float v1 = acc[2*f+1][r] + eps[f*32 + 2*lr + 1];
        s += v0 + v1; ss += v0*v0 + v1*v1;
      }
      #pragma unroll
      for (int off=1; off<16; off<<=1){ s += __shfl_xor(s, off); ss += __shfl_xor(ss, off); }
      float mean = s * (1.0f/192.0f);
      float var  = ss * (1.0f/192.0f) - mean*mean;
      float rinv = rsqrtf(var + 1e-5f);
      if (row < M){
        size_t base = (size_t)row*192;
        #pragma unroll
        for (int f=0; f<6; f++){
          int c0 = f*32 + 2*lr;
          float v0 = acc[2*f][r]   + eps[c0];
          float v1 = acc[2*f+1][r] + eps[c0 + 1];
          f32x2 xm = *(const f32x2*)&xmid[base + c0];
          f32x2 o;
          o[0] = xm[0] + (v0 - mean)*rinv*eps[192 + c0]     + eps[384 + c0];
          o[1] = xm[1] + (v1 - mean)*rinv*eps[192 + c0 + 1] + eps[384 + c0 + 1];
          *(f32x2*)&outF[base + c0] = o;
        }
      }
    }
  }
}

extern "C" void kernel_launch(void* const* d_in, const int* in_sizes, int n_in,
                              void* d_out, int out_size, void* d_ws, size_t ws_size,
                              hipStream_t stream)
{
  const float* x_in    = (const float*)d_in[0];
  const float* qkvw    = (const float*)d_in[1];
  const float* qkvbias = (const float*)d_in[2];
  const float* projw   = (const float*)d_in[3];
  const float* projbias= (const float*)d_in[4];
  const float* btab    = (const float*)d_in[5];
  const float* n1g = (const float*)d_in[6];
  const float* n1b = (const float*)d_in[7];
  const float* n2g = (const float*)d_in[8];
  const float* n2b = (const float*)d_in[9];
  const float* w1  = (const float*)d_in[10];
  const float* b1  = (const float*)d_in[11];
  const float* w2  = (const float*)d_in[12];
  const float* b2  = (const float*)d_in[13];
  float* outp = (float*)d_out;

  const size_t REG_A = (size_t)NTOKW*192;
  const size_t REG_B = (size_t)NTOKW*576;
  const size_t W_QT  = (size_t)2*576*192;
  const size_t W_PT  = (size_t)2*192*192;
  const size_t W_1T  = (size_t)2*768*192;
  const size_t W_2T  = (size_t)2*192*768;
  const size_t TOT_SH = REG_A + REG_B + W_QT + W_PT + W_1T + W_2T;
  const size_t NEEDED = TOT_SH*2 + (size_t)NTOK*192*4;
  if (ws_size < NEEDED) return;

  unsigned short* ws16 = (unsigned short*)d_ws;
  size_t off = 0;
  unsigned short* regA = ws16 + off; off += REG_A;
  unsigned short* regB = ws16 + off; off += REG_B;
  unsigned short* wqt  = ws16 + off; off += W_QT;
  unsigned short* wpt  = ws16 + off; off += W_PT;
  unsigned short* w1t  = ws16 + off; off += W_1T;
  unsigned short* w2t  = ws16 + off; off += W_2T;
  float* xmidf = (float*)(ws16 + off);
  unsigned short* bw = (unsigned short*)xmidf;   // alias: dead before unwin_ln writes (17.7MB)

  for (int dep=0; dep<2; dep++){
    transp<<<(192*576+255)/256,256,0,stream>>>(qkvw + (size_t)dep*192*576,
                                               wqt + (size_t)dep*576*192, 192, 576);
    transp<<<(192*192+255)/256,256,0,stream>>>(projw + (size_t)dep*192*192,
                                               wpt + (size_t)dep*192*192, 192, 192);
    transp<<<(192*768+255)/256,256,0,stream>>>(w1 + (size_t)dep*192*768,
                                               w1t + (size_t)dep*768*192, 192, 768);
    transp<<<(768*192+255)/256,256,0,stream>>>(w2 + (size_t)dep*768*192,
                                               w2t + (size_t)dep*192*768, 768, 192);
  }

  for (int dep=0; dep<2; dep++){
    int roll = dep;
    const float* xs = (dep==0) ? x_in : outp;
    float* xout = outp;

    gather_win<<<NTOKW*24/256, 256, 0, stream>>>(xs, regA, roll);

    dim3 g1(NTOKW/128, 3);     // N=576
    gemm_k192<<<g1, 512, 0, stream>>>(regA, wqt + (size_t)dep*576*192,
                                      qkvbias + dep*576, regB, 576);

    bias_pre<<<(384*9*64*40)/256, 256, 0, stream>>>(btab + (size_t)dep*3312*384, bw, roll);

    attn_win<<<960*6, 576, 0, stream>>>(regB, bw, regA);

    dim3 g2(NTOKW/128, 1);     // N=192
    gemm_k192<<<g2, 512, 0, stream>>>(regA, wpt + (size_t)dep*192*192,
                                      projbias + dep*192, regB, 192);

    unwin_ln<<<NTOK/4, 256, 0, stream>>>(regB, xs, n1g + dep*192, n1b + dep*192,
                                         xmidf, regA, roll);

    mlp_fused_ln<<<(NTOK+127)/128, 256, 0, stream>>>(
        regA, w1t + (size_t)dep*768*192, b1 + dep*768,
        w2t + (size_t)dep*192*768, b2 + dep*192,
        xmidf, n2g + dep*192, n2b + dep*192, xout, NTOK);
  }
}

// Round 12
// 1132.079 us; speedup vs baseline: 1.0466x; 1.0466x over previous
//
#include <hip/hip_runtime.h>
#include <math.h>

#define NTOK   131040   // 8*91*180
#define NTOKW  138240   // 15*64*144

typedef __attribute__((ext_vector_type(8))) short bf16x8;
typedef __attribute__((ext_vector_type(8))) unsigned short u16x8;
typedef __attribute__((ext_vector_type(4))) float f32x4;
typedef __attribute__((ext_vector_type(2))) float f32x2;

__device__ __forceinline__ float b2f(unsigned short u){
  union { unsigned u; float f; } v; v.u = ((unsigned)u) << 16; return v.f;
}
__device__ __forceinline__ unsigned short f2b(float f){
  union { float f; unsigned u; } v; v.f = f;
  unsigned r = v.u + 0x7FFFu + ((v.u >> 16) & 1u);
  return (unsigned short)(r >> 16);
}
// tanh-GELU via rcpf (no f32 div sequence); |err vs erf-GELU| ~3e-4
__device__ __forceinline__ float gelu_fast(float x){
  float t = 0.79788456080286536f * (x + 0.044715f * x * x * x);
  float e = __expf(2.0f * t);
  float th = 1.0f - 2.0f * __builtin_amdgcn_rcpf(e + 1.0f);
  return 0.5f * x * (1.0f + th);
}
__device__ __forceinline__ unsigned pk_bf16(float lo, float hi){
  unsigned r;
  asm("v_cvt_pk_bf16_f32 %0, %1, %2" : "=v"(r) : "v"(lo), "v"(hi));
  return r;
}
__device__ __forceinline__ void lds_barrier(){
  asm volatile("s_waitcnt lgkmcnt(0)" ::: "memory");
  __builtin_amdgcn_sched_barrier(0);
  __builtin_amdgcn_s_barrier();
  __builtin_amdgcn_sched_barrier(0);
}

// transpose-cast: dst[n][k] = (bf16)src[k][n]
__global__ __launch_bounds__(256) void transp(const float* __restrict__ src,
                                              unsigned short* __restrict__ dst,
                                              int K, int N){
  int i = blockIdx.x*256 + threadIdx.x;
  if (i < K*N){
    int n = i / K, k = i % K;
    dst[i] = f2b(src[(size_t)k*N + n]);
  }
}

// precompute bias+mask in MFMA-fragment layout:
// bw[(((slice*9 + wv)*5 + vec)*64 + lane)*8 + elem], e = vec*8+elem = ct*4+r (<36)
__global__ __launch_bounds__(256) void bias_pre(
    const float* __restrict__ btab,
    unsigned short* __restrict__ bw,
    int roll)
{
  int gid = blockIdx.x*256 + threadIdx.x;   // < 384*9*64*40
  int e    = gid % 40;
  int rem  = gid / 40;
  int lane = rem % 64;
  int rem2 = rem / 64;
  int wv   = rem2 % 9;
  int slice= rem2 / 9;
  unsigned short out = 0;
  if (e < 36){
    int ct = e >> 2, r = e & 3;
    int i = wv*16 + (lane>>4)*4 + r;
    int j = ct*16 + (lane & 15);
    int tw = slice / 6, head = slice % 6;
    int ia = i/72, ib = (i%72)/12, ic = i%12;
    int ja = j/72, jb = (j%72)/12, jc = j%12;
    int idx = (ia + 2*ja)*828 + (ib + 6*jb)*23 + (ic - jc + 11);
    float v = btab[(size_t)idx*384 + tw*6 + head];
    if (roll){
      int nz = tw >> 4, nh = tw & 15;
      int zi = nz*2+ia, hi = nh*6+ib, zj = nz*2+ja, hj = nh*6+jb;
      int ri = 3*((zi<6)?0:((zi<7)?1:2)) + ((hi<90)?0:((hi<93)?1:2));
      int rj = 3*((zj<6)?0:((zj<7)?1:2)) + ((hj<90)?0:((hj<93)?1:2));
      if (ri != rj) v -= 100.0f;
    }
    out = f2b(v);
  }
  int vec = e >> 3, elem = e & 7;
  size_t di = ((((size_t)slice*9 + wv)*5 + vec)*64 + lane)*8 + elem;
  bw[di] = out;
}

// window-partition gather (+pad +roll), fp32 -> bf16
__global__ __launch_bounds__(256) void gather_win(const float* __restrict__ x,
                                                  unsigned short* __restrict__ xw,
                                                  int roll){
  int gid = blockIdx.x*256 + threadIdx.x;
  int row = gid / 24;
  int dp  = gid % 24;
  int tok = row % 144;
  int wt  = row / 144;
  int tw  = wt & 63;
  int w   = wt >> 6;
  int nz = tw >> 4, nh = tw & 15;
  int wz = tok / 72; int rem = tok % 72; int wh = rem / 12; int ww = rem % 12;
  int z = nz*2 + wz, h = nh*6 + wh, wc = w*12 + ww;
  if (roll){ z = (z+1)&7; h = (h+3)%96; wc = (wc+6)%180; }
  int d0 = dp*8;
  u16x8 o;
  if (h < 91){
    const float* s = x + ((size_t)((z*91 + h)*180 + wc))*192 + d0;
    #pragma unroll
    for (int i=0;i<8;i++) o[i] = f2b(s[i]);
  } else {
    #pragma unroll
    for (int i=0;i<8;i++) o[i] = 0;
  }
  *(u16x8*)(xw + (size_t)row*192 + d0) = o;
}

// K=192 GEMM: C[M x N] = A[M x 192] @ Bt[N x 192]^T + bias (qkv path)
__global__ __launch_bounds__(512) void gemm_k192(
    const unsigned short* __restrict__ A,
    const unsigned short* __restrict__ Bt,
    const float* __restrict__ bias,
    unsigned short* __restrict__ C,
    int N)
{
  __shared__ unsigned short Bst[192][200];
  int m0 = blockIdx.x * 128;
  int n0 = blockIdx.y * 192;
  int t = threadIdx.x;
  int lane = t & 63, w = t >> 6;
  int wm = w >> 2, wn = w & 3;
  int lg = lane >> 4, lr = lane & 15;

  #pragma unroll
  for (int i=0;i<9;i++){
    int idx = t + i*512;
    int r = idx / 24, c = (idx % 24)*8;
    *(u16x8*)&Bst[r][c] = *(const u16x8*)(Bt + (size_t)(n0 + r)*192 + c);
  }
  __syncthreads();

  const unsigned short* aRow = A + (size_t)(m0 + wm*64 + lr)*192 + lg*8;

  f32x4 acc[4][3];
  #pragma unroll
  for (int a=0;a<4;a++)
    #pragma unroll
    for (int b=0;b<3;b++) acc[a][b] = (f32x4){0.f,0.f,0.f,0.f};

  bf16x8 aP[2][6];
  #pragma unroll
  for (int ks=0; ks<6; ks++) aP[0][ks] = *(const bf16x8*)(aRow + ks*32);

  #pragma unroll
  for (int rt=0; rt<4; rt++){
    if (rt < 3){
      const unsigned short* an = aRow + (size_t)(rt+1)*16*192;
      #pragma unroll
      for (int ks=0; ks<6; ks++) aP[(rt+1)&1][ks] = *(const bf16x8*)(an + ks*32);
    }
    #pragma unroll
    for (int ks=0; ks<6; ks++){
      bf16x8 b0 = *(const bf16x8*)&Bst[wn*48 +      lr][ks*32 + lg*8];
      bf16x8 b1 = *(const bf16x8*)&Bst[wn*48 + 16 + lr][ks*32 + lg*8];
      bf16x8 b2 = *(const bf16x8*)&Bst[wn*48 + 32 + lr][ks*32 + lg*8];
      bf16x8 af = aP[rt&1][ks];
      acc[rt][0] = __builtin_amdgcn_mfma_f32_16x16x32_bf16(af, b0, acc[rt][0], 0,0,0);
      acc[rt][1] = __builtin_amdgcn_mfma_f32_16x16x32_bf16(af, b1, acc[rt][1], 0,0,0);
      acc[rt][2] = __builtin_amdgcn_mfma_f32_16x16x32_bf16(af, b2, acc[rt][2], 0,0,0);
    }
  }

  #pragma unroll
  for (int rt=0; rt<4; rt++){
    #pragma unroll
    for (int fn=0; fn<3; fn++){
      int colg = n0 + wn*48 + fn*16 + lr;
      float bv = bias[colg];
      #pragma unroll
      for (int r=0;r<4;r++){
        int rowg = m0 + wm*64 + rt*16 + lg*4 + r;
        C[(size_t)rowg*N + colg] = f2b(acc[rt][fn][r] + bv);
      }
    }
  }
}

// fused proj GEMM + un-window + LN1 + residual:
//   y = attnout @ Wp^T + bp ; for valid tokens: out = xsrc + LN(y)
// writes xmidf (f32, token order) and xmidb (bf16, token order)
__global__ __launch_bounds__(512) void proj_ln(
    const unsigned short* __restrict__ A,    // [NTOKW][192] attn out
    const unsigned short* __restrict__ Bt,   // [192][192]
    const float* __restrict__ bias,          // [192]
    const float* __restrict__ xsrc,          // [NTOK][192] f32 trunk
    const float* __restrict__ g,             // [192] LN gamma
    const float* __restrict__ bb,            // [192] LN beta
    float* __restrict__ outf,                // xmidf
    unsigned short* __restrict__ outb,       // xmidb
    int roll)
{
  __shared__ unsigned short Bst[192][200];
  __shared__ float Psum[128][4];
  __shared__ float Psq [128][4];
  int m0 = blockIdx.x * 128;
  int t = threadIdx.x;
  int lane = t & 63, w = t >> 6;
  int wm = w >> 2, wn = w & 3;
  int lg = lane >> 4, lr = lane & 15;

  #pragma unroll
  for (int i=0;i<9;i++){
    int idx = t + i*512;
    int r = idx / 24, c = (idx % 24)*8;
    *(u16x8*)&Bst[r][c] = *(const u16x8*)(Bt + (size_t)r*192 + c);
  }
  __syncthreads();

  const unsigned short* aRow = A + (size_t)(m0 + wm*64 + lr)*192 + lg*8;

  f32x4 acc[4][3];
  #pragma unroll
  for (int a=0;a<4;a++)
    #pragma unroll
    for (int b=0;b<3;b++) acc[a][b] = (f32x4){0.f,0.f,0.f,0.f};

  bf16x8 aP[2][6];
  #pragma unroll
  for (int ks=0; ks<6; ks++) aP[0][ks] = *(const bf16x8*)(aRow + ks*32);

  #pragma unroll
  for (int rt=0; rt<4; rt++){
    if (rt < 3){
      const unsigned short* an = aRow + (size_t)(rt+1)*16*192;
      #pragma unroll
      for (int ks=0; ks<6; ks++) aP[(rt+1)&1][ks] = *(const bf16x8*)(an + ks*32);
    }
    #pragma unroll
    for (int ks=0; ks<6; ks++){
      bf16x8 b0 = *(const bf16x8*)&Bst[wn*48 +      lr][ks*32 + lg*8];
      bf16x8 b1 = *(const bf16x8*)&Bst[wn*48 + 16 + lr][ks*32 + lg*8];
      bf16x8 b2 = *(const bf16x8*)&Bst[wn*48 + 32 + lr][ks*32 + lg*8];
      bf16x8 af = aP[rt&1][ks];
      acc[rt][0] = __builtin_amdgcn_mfma_f32_16x16x32_bf16(af, b0, acc[rt][0], 0,0,0);
      acc[rt][1] = __builtin_amdgcn_mfma_f32_16x16x32_bf16(af, b1, acc[rt][1], 0,0,0);
      acc[rt][2] = __builtin_amdgcn_mfma_f32_16x16x32_bf16(af, b2, acc[rt][2], 0,0,0);
    }
  }

  // add bias, per-row partial sums over this wave's 48 cols
  float bv[3];
  #pragma unroll
  for (int fn=0; fn<3; fn++) bv[fn] = bias[wn*48 + fn*16 + lr];

  float sp[4][4], sq[4][4];
  #pragma unroll
  for (int rt=0; rt<4; rt++){
    #pragma unroll
    for (int r=0;r<4;r++){
      float s = 0.f, ss = 0.f;
      #pragma unroll
      for (int fn=0; fn<3; fn++){
        float v = acc[rt][fn][r] + bv[fn];
        acc[rt][fn][r] = v;          // keep biased value
        s += v; ss += v*v;
      }
      #pragma unroll
      for (int off=1; off<16; off<<=1){
        s  += __shfl_xor(s,  off);
        ss += __shfl_xor(ss, off);
      }
      sp[rt][r] = s; sq[rt][r] = ss;
    }
  }
  if (lr == 0){
    #pragma unroll
    for (int rt=0; rt<4; rt++)
      #pragma unroll
      for (int r=0;r<4;r++){
        int row = wm*64 + rt*16 + lg*4 + r;
        Psum[row][wn] = sp[rt][r];
        Psq [row][wn] = sq[rt][r];
      }
  }
  lds_barrier();

  #pragma unroll
  for (int rt=0; rt<4; rt++){
    #pragma unroll
    for (int r=0;r<4;r++){
      int row = wm*64 + rt*16 + lg*4 + r;
      f32x4 s4 = *(const f32x4*)&Psum[row][0];
      f32x4 q4 = *(const f32x4*)&Psq [row][0];
      float s  = s4[0]+s4[1]+s4[2]+s4[3];
      float ss = q4[0]+q4[1]+q4[2]+q4[3];
      float mean = s * (1.0f/192.0f);
      float var  = ss * (1.0f/192.0f) - mean*mean;
      float rinv = rsqrtf(var + 1e-5f);

      // window row -> token (inverse roll), skip padding
      int grow = m0 + row;
      int wt = grow / 144, tok = grow % 144;
      int tw = wt & 63, wwi = wt >> 6;
      int nz = tw >> 4, nh = tw & 15;
      int wz = tok / 72; int trem = tok % 72; int wh = trem / 12; int wwp = trem % 12;
      int zz = nz*2 + wz, hh = nh*6 + wh, ww2 = wwi*12 + wwp;
      int z, h, wc;
      if (roll){ z = (zz+1)&7; h = (hh+3)%96; wc = (ww2+6)%180; }
      else     { z = zz; h = hh; wc = ww2; }
      if (h < 91){
        size_t tb = ((size_t)(z*91 + h)*180 + wc)*192;
        #pragma unroll
        for (int fn=0; fn<3; fn++){
          int col = wn*48 + fn*16 + lr;
          float v = acc[rt][fn][r];
          float o = xsrc[tb + col] + (v - mean)*rinv*g[col] + bb[col];
          outf[tb + col] = o;
          outb[tb + col] = f2b(o);
        }
      }
    }
  }
}

// fused windowed attention: one block per (window-pair, head). 9 waves.
__global__ __launch_bounds__(576) void attn_win(
    const unsigned short* __restrict__ qkv,
    const unsigned short* __restrict__ bw,
    unsigned short* __restrict__ outp)
{
  __shared__ union {
    struct { unsigned short Qs[144][32]; unsigned short Ks[144][40]; } qk;
    unsigned short Ps[144][160];
  } U;
  __shared__ unsigned short Vst[32][160];

  int b = blockIdx.x;
  int head = b % 6;
  int wt = b / 6;
  int tw = wt & 63;
  int t = threadIdx.x;
  int lane = t & 63;
  int wv = t >> 6;
  int lg = lane >> 4, lr = lane & 15;

  {
    int tok = t >> 2, c0 = (t & 3)*8;
    size_t base = ((size_t)wt*144 + tok)*576 + head*32 + c0;
    u16x8 qv = *(const u16x8*)(qkv + base);
    u16x8 kv = *(const u16x8*)(qkv + base + 192);
    u16x8 vv = *(const u16x8*)(qkv + base + 384);
    u16x8 qs;
    #pragma unroll
    for (int i=0;i<8;i++) qs[i] = f2b(b2f(qv[i]) * 0.17677669529663687f);
    *(u16x8*)&U.qk.Qs[tok][c0] = qs;
    *(u16x8*)&U.qk.Ks[tok][c0] = kv;
    #pragma unroll
    for (int i=0;i<8;i++) Vst[c0+i][tok] = vv[i];
  }
  if (t < 512) Vst[t >> 4][144 + (t & 15)] = 0;

  u16x8 bv0, bv1, bv2, bv3, bv4;
  {
    size_t sbase = ((((size_t)(tw*6 + head))*9 + wv)*5*64 + lane)*8;
    bv0 = *(const u16x8*)(bw + sbase);
    bv1 = *(const u16x8*)(bw + sbase + 64*8);
    bv2 = *(const u16x8*)(bw + sbase + 2*64*8);
    bv3 = *(const u16x8*)(bw + sbase + 3*64*8);
    bv4 = *(const u16x8*)(bw + sbase + 4*64*8);
  }
  __syncthreads();

  float s[9][4];
  {
    bf16x8 a = *(const bf16x8*)&U.qk.Qs[wv*16 + lr][lg*8];
    #pragma unroll
    for (int ct=0; ct<9; ct++){
      bf16x8 bb = *(const bf16x8*)&U.qk.Ks[ct*16 + lr][lg*8];
      f32x4 d = {0.f,0.f,0.f,0.f};
      d = __builtin_amdgcn_mfma_f32_16x16x32_bf16(a, bb, d, 0,0,0);
      s[ct][0]=d[0]; s[ct][1]=d[1]; s[ct][2]=d[2]; s[ct][3]=d[3];
    }
  }

  #pragma unroll
  for (int ct=0; ct<9; ct++){
    #pragma unroll
    for (int r=0;r<4;r++){
      const int e = ct*4 + r;
      unsigned short bu =
        (e < 8)  ? bv0[e & 7] :
        (e < 16) ? bv1[e & 7] :
        (e < 24) ? bv2[e & 7] :
        (e < 32) ? bv3[e & 7] : bv4[e & 7];
      s[ct][r] += b2f(bu);
    }
  }

  float mx[4] = {-1e30f,-1e30f,-1e30f,-1e30f};
  #pragma unroll
  for (int ct=0; ct<9; ct++)
    #pragma unroll
    for (int r=0;r<4;r++) mx[r] = fmaxf(mx[r], s[ct][r]);
  #pragma unroll
  for (int off=1; off<16; off<<=1)
    #pragma unroll
    for (int r=0;r<4;r++) mx[r] = fmaxf(mx[r], __shfl_xor(mx[r], off));
  float sm[4] = {0.f,0.f,0.f,0.f};
  #pragma unroll
  for (int ct=0; ct<9; ct++)
    #pragma unroll
    for (int r=0;r<4;r++){ s[ct][r] = __expf(s[ct][r] - mx[r]); sm[r] += s[ct][r]; }
  #pragma unroll
  for (int off=1; off<16; off<<=1)
    #pragma unroll
    for (int r=0;r<4;r++) sm[r] += __shfl_xor(sm[r], off);
  float inv[4];
  #pragma unroll
  for (int r=0;r<4;r++) inv[r] = 1.0f / sm[r];

  lds_barrier();

  #pragma unroll
  for (int ct=0; ct<9; ct++)
    #pragma unroll
    for (int r=0;r<4;r++)
      U.Ps[wv*16 + lg*4 + r][ct*16 + lr] = f2b(s[ct][r] * inv[r]);
  #pragma unroll
  for (int r=0;r<4;r++) U.Ps[wv*16 + lg*4 + r][144 + lr] = 0;
  __syncthreads();

  #pragma unroll
  for (int ct2=0; ct2<2; ct2++){
    f32x4 o = {0.f,0.f,0.f,0.f};
    #pragma unroll
    for (int kt=0; kt<5; kt++){
      bf16x8 a  = *(const bf16x8*)&U.Ps[wv*16 + lr][kt*32 + lg*8];
      bf16x8 bb = *(const bf16x8*)&Vst[ct2*16 + lr][kt*32 + lg*8];
      o = __builtin_amdgcn_mfma_f32_16x16x32_bf16(a, bb, o, 0,0,0);
    }
    size_t rb = ((size_t)wt*144 + wv*16 + lg*4)*192 + head*32 + ct2*16 + lr;
    #pragma unroll
    for (int r=0;r<4;r++) outp[rb + (size_t)r*192] = f2b(o[r]);
  }
}

// fused MLP + final LN + residual: out = xmid + LN( gelu(A@W1+b1) @ W2 + b2 )
// 256 rows/block, 8 waves x 32 rows; double-buffered weight chunks, 1 barrier/iter.
__global__ __launch_bounds__(512) void mlp_fused_ln(
    const unsigned short* __restrict__ A,    // [M][192] bf16
    const unsigned short* __restrict__ W1t,  // [768][192]
    const float* __restrict__ bias1,         // [768]
    const unsigned short* __restrict__ W2t,  // [192][768]
    const float* __restrict__ mbias2,        // [192]
    const float* __restrict__ xmid,          // [M][192] f32
    const float* __restrict__ lng,           // [192]
    const float* __restrict__ lnb,           // [192]
    float* __restrict__ outF,                // [M][192] f32
    int M)
{
  __shared__ unsigned short W1s[2][32][196];
  __shared__ unsigned short W2s[2][192][44];
  __shared__ unsigned short Hs[8][32][40];
  __shared__ float b1s[768];
  __shared__ float eps[576];                // [mb2 | lng | lnb]
  int m0 = blockIdx.x*256;
  int t = threadIdx.x, lane = t & 63, w = t >> 6;
  int lg = lane >> 4, lr = lane & 15;

  bf16x8 afrA[6], afrB[6];
  {
    int ra = m0 + w*32 + lr, rb = ra + 16;
    if (ra < M){
      const unsigned short* ap = A + (size_t)ra*192 + lg*8;
      #pragma unroll
      for (int ks=0; ks<6; ks++) afrA[ks] = *(const bf16x8*)(ap + ks*32);
    } else {
      #pragma unroll
      for (int ks=0; ks<6; ks++)
        #pragma unroll
        for (int j=0;j<8;j++) afrA[ks][j] = 0;
    }
    if (rb < M){
      const unsigned short* ap = A + (size_t)rb*192 + lg*8;
      #pragma unroll
      for (int ks=0; ks<6; ks++) afrB[ks] = *(const bf16x8*)(ap + ks*32);
    } else {
      #pragma unroll
      for (int ks=0; ks<6; ks++)
        #pragma unroll
        for (int j=0;j<8;j++) afrB[ks][j] = 0;
    }
  }

  b1s[t] = bias1[t];
  if (t < 256) b1s[512 + t] = bias1[512 + t];
  if (t < 192){ eps[t] = mbias2[t]; eps[192 + t] = lng[t]; eps[384 + t] = lnb[t]; }

  int i1r[2], i1c[2], i2r[2], i2c[2];
  #pragma unroll
  for (int i=0;i<2;i++){
    int idx = t + i*512;
    i1r[i] = idx/24; i1c[i] = (idx%24)*8;
    i2r[i] = idx/4;  i2c[i] = (idx&3)*8;
  }
  bool g2nd = (t + 512) < 768;

  {
    u16x8 a0 = *(const u16x8*)(W1t + (size_t)i1r[0]*192 + i1c[0]);
    u16x8 b0 = *(const u16x8*)(W2t + (size_t)i2r[0]*768 + i2c[0]);
    *(u16x8*)&W1s[0][i1r[0]][i1c[0]] = a0;
    *(u16x8*)&W2s[0][i2r[0]][i2c[0]] = b0;
    if (g2nd){
      u16x8 a1 = *(const u16x8*)(W1t + (size_t)i1r[1]*192 + i1c[1]);
      u16x8 b1v = *(const u16x8*)(W2t + (size_t)i2r[1]*768 + i2c[1]);
      *(u16x8*)&W1s[0][i1r[1]][i1c[1]] = a1;
      *(u16x8*)&W2s[0][i2r[1]][i2c[1]] = b1v;
    }
  }
  lds_barrier();

  f32x4 accA[12], accB[12];
  #pragma unroll
  for (int i=0;i<12;i++){ accA[i] = (f32x4){0.f,0.f,0.f,0.f}; accB[i] = (f32x4){0.f,0.f,0.f,0.f}; }

  u16x8 w1r[2], w2r[2];

  for (int it=0; it<24; ++it){
    int cur = it & 1;
    if (it < 23){
      int hc2 = (it+1)*32;
      w1r[0] = *(const u16x8*)(W1t + (size_t)(hc2 + i1r[0])*192 + i1c[0]);
      w2r[0] = *(const u16x8*)(W2t + (size_t)i2r[0]*768 + hc2 + i2c[0]);
      if (g2nd){
        w1r[1] = *(const u16x8*)(W1t + (size_t)(hc2 + i1r[1])*192 + i1c[1]);
        w2r[1] = *(const u16x8*)(W2t + (size_t)i2r[1]*768 + hc2 + i2c[1]);
      }
    }

    int hc = it*32;
    f32x4 h0a = (f32x4){0.f,0.f,0.f,0.f}, h1a = h0a, h0b = h0a, h1b = h0a;
    #pragma unroll
    for (int ks=0; ks<6; ks++){
      bf16x8 b0  = *(const bf16x8*)&W1s[cur][2*lr    ][ks*32 + lg*8];
      bf16x8 b1f = *(const bf16x8*)&W1s[cur][2*lr + 1][ks*32 + lg*8];
      h0a = __builtin_amdgcn_mfma_f32_16x16x32_bf16(afrA[ks], b0,  h0a, 0,0,0);
      h1a = __builtin_amdgcn_mfma_f32_16x16x32_bf16(afrA[ks], b1f, h1a, 0,0,0);
      h0b = __builtin_amdgcn_mfma_f32_16x16x32_bf16(afrB[ks], b0,  h0b, 0,0,0);
      h1b = __builtin_amdgcn_mfma_f32_16x16x32_bf16(afrB[ks], b1f, h1b, 0,0,0);
    }
    float bb0 = b1s[hc + 2*lr];
    float bb1 = b1s[hc + 2*lr + 1];
    #pragma unroll
    for (int r=0;r<4;r++){
      *(unsigned*)&Hs[w][lg*4 + r][2*lr] =
          pk_bf16(gelu_fast(h0a[r] + bb0), gelu_fast(h1a[r] + bb1));
      *(unsigned*)&Hs[w][16 + lg*4 + r][2*lr] =
          pk_bf16(gelu_fast(h0b[r] + bb0), gelu_fast(h1b[r] + bb1));
    }
    bf16x8 paA = *(const bf16x8*)&Hs[w][lr][lg*8];
    bf16x8 paB = *(const bf16x8*)&Hs[w][16 + lr][lg*8];
    #pragma unroll
    for (int f=0; f<6; f++){
      bf16x8 c0 = *(const bf16x8*)&W2s[cur][f*32 + 2*lr    ][lg*8];
      bf16x8 c1 = *(const bf16x8*)&W2s[cur][f*32 + 2*lr + 1][lg*8];
      accA[2*f]   = __builtin_amdgcn_mfma_f32_16x16x32_bf16(paA, c0, accA[2*f],   0,0,0);
      accA[2*f+1] = __builtin_amdgcn_mfma_f32_16x16x32_bf16(paA, c1, accA[2*f+1], 0,0,0);
      accB[2*f]   = __builtin_amdgcn_mfma_f32_16x16x32_bf16(paB, c0, accB[2*f],   0,0,0);
      accB[2*f+1] = __builtin_amdgcn_mfma_f32_16x16x32_bf16(paB, c1, accB[2*f+1], 0,0,0);
    }

    if (it < 23){
      int nxt = cur ^ 1;
      *(u16x8*)&W1s[nxt][i1r[0]][i1c[0]] = w1r[0];
      *(u16x8*)&W2s[nxt][i2r[0]][i2c[0]] = w2r[0];
      if (g2nd){
        *(u16x8*)&W1s[nxt][i1r[1]][i1c[1]] = w1r[1];
        *(u16x8*)&W2s[nxt][i2r[1]][i2c[1]] = w2r[1];
      }
    }
    lds_barrier();
  }

  #pragma unroll
  for (int gsel=0; gsel<2; gsel++){
    f32x4* acc = gsel ? accB : accA;
    #pragma unroll
    for (int r=0;r<4;r++){
      int row = m0 + w*32 + gsel*16 + lg*4 + r;
      float s = 0.f, ss = 0.f;
      #pragma unroll
      for (int f=0; f<6; f++){
        float v0 = acc[2*f][r]   + eps[f*32 + 2*lr];
        float v1 = acc[2*f+1][r] + eps[f*32 + 2*lr + 1];
        s += v0 + v1; ss += v0*v0 + v1*v1;
      }
      #pragma unroll
      for (int off=1; off<16; off<<=1){ s += __shfl_xor(s, off); ss += __shfl_xor(ss, off); }
      float mean = s * (1.0f/192.0f);
      float var  = ss * (1.0f/192.0f) - mean*mean;
      float rinv = rsqrtf(var + 1e-5f);
      if (row < M){
        size_t base = (size_t)row*192;
        #pragma unroll
        for (int f=0; f<6; f++){
          int c0 = f*32 + 2*lr;
          float v0 = acc[2*f][r]   + eps[c0];
          float v1 = acc[2*f+1][r] + eps[c0 + 1];
          f32x2 xm = *(const f32x2*)&xmid[base + c0];
          f32x2 o;
          o[0] = xm[0] + (v0 - mean)*rinv*eps[192 + c0]     + eps[384 + c0];
          o[1] = xm[1] + (v1 - mean)*rinv*eps[192 + c0 + 1] + eps[384 + c0 + 1];
          *(f32x2*)&outF[base + c0] = o;
        }
      }
    }
  }
}

extern "C" void kernel_launch(void* const* d_in, const int* in_sizes, int n_in,
                              void* d_out, int out_size, void* d_ws, size_t ws_size,
                              hipStream_t stream)
{
  const float* x_in    = (const float*)d_in[0];
  const float* qkvw    = (const float*)d_in[1];
  const float* qkvbias = (const float*)d_in[2];
  const float* projw   = (const float*)d_in[3];
  const float* projbias= (const float*)d_in[4];
  const float* btab    = (const float*)d_in[5];
  const float* n1g = (const float*)d_in[6];
  const float* n1b = (const float*)d_in[7];
  const float* n2g = (const float*)d_in[8];
  const float* n2b = (const float*)d_in[9];
  const float* w1  = (const float*)d_in[10];
  const float* b1  = (const float*)d_in[11];
  const float* w2  = (const float*)d_in[12];
  const float* b2  = (const float*)d_in[13];
  float* outp = (float*)d_out;

  const size_t REG_A = (size_t)NTOKW*192;
  const size_t REG_B = (size_t)NTOKW*576;
  const size_t W_QT  = (size_t)2*576*192;
  const size_t W_PT  = (size_t)2*192*192;
  const size_t W_1T  = (size_t)2*768*192;
  const size_t W_2T  = (size_t)2*192*768;
  const size_t TOT_SH = REG_A + REG_B + W_QT + W_PT + W_1T + W_2T;
  const size_t NEEDED = TOT_SH*2 + (size_t)NTOK*192*4;
  if (ws_size < NEEDED) return;

  unsigned short* ws16 = (unsigned short*)d_ws;
  size_t off = 0;
  unsigned short* regA = ws16 + off; off += REG_A;   // xw / attn-out
  unsigned short* regB = ws16 + off; off += REG_B;   // qkv-out / xmidb
  unsigned short* wqt  = ws16 + off; off += W_QT;
  unsigned short* wpt  = ws16 + off; off += W_PT;
  unsigned short* w1t  = ws16 + off; off += W_1T;
  unsigned short* w2t  = ws16 + off; off += W_2T;
  float* xmidf = (float*)(ws16 + off);
  unsigned short* bw = (unsigned short*)xmidf;   // alias: dead before proj_ln writes xmidf

  for (int dep=0; dep<2; dep++){
    transp<<<(192*576+255)/256,256,0,stream>>>(qkvw + (size_t)dep*192*576,
                                               wqt + (size_t)dep*576*192, 192, 576);
    transp<<<(192*192+255)/256,256,0,stream>>>(projw + (size_t)dep*192*192,
                                               wpt + (size_t)dep*192*192, 192, 192);
    transp<<<(192*768+255)/256,256,0,stream>>>(w1 + (size_t)dep*192*768,
                                               w1t + (size_t)dep*768*192, 192, 768);
    transp<<<(768*192+255)/256,256,0,stream>>>(w2 + (size_t)dep*768*192,
                                               w2t + (size_t)dep*192*768, 768, 192);
  }

  for (int dep=0; dep<2; dep++){
    int roll = dep;
    const float* xs = (dep==0) ? x_in : outp;
    float* xout = outp;

    gather_win<<<NTOKW*24/256, 256, 0, stream>>>(xs, regA, roll);

    dim3 g1(NTOKW/128, 3);     // N=576
    gemm_k192<<<g1, 512, 0, stream>>>(regA, wqt + (size_t)dep*576*192,
                                      qkvbias + dep*576, regB, 576);

    bias_pre<<<(384*9*64*40)/256, 256, 0, stream>>>(btab + (size_t)dep*3312*384, bw, roll);

    attn_win<<<960*6, 576, 0, stream>>>(regB, bw, regA);

    // fused proj + un-window + LN1 + residual -> xmidf (f32) + regB (bf16)
    proj_ln<<<NTOKW/128, 512, 0, stream>>>(regA, wpt + (size_t)dep*192*192,
                                           projbias + dep*192, xs,
                                           n1g + dep*192, n1b + dep*192,
                                           xmidf, regB, roll);

    mlp_fused_ln<<<(NTOK+255)/256, 512, 0, stream>>>(
        regB, w1t + (size_t)dep*768*192, b1 + dep*768,
        w2t + (size_t)dep*192*768, b2 + dep*192,
        xmidf, n2g + dep*192, n2b + dep*192, xout, NTOK);
  }
}

// Round 13
// 1052.660 us; speedup vs baseline: 1.1256x; 1.0754x over previous
//
#include <hip/hip_runtime.h>
#include <math.h>

#define NTOK   131040   // 8*91*180
#define NTOKW  138240   // 15*64*144

typedef __attribute__((ext_vector_type(8))) short bf16x8;
typedef __attribute__((ext_vector_type(8))) unsigned short u16x8;
typedef __attribute__((ext_vector_type(4))) float f32x4;
typedef __attribute__((ext_vector_type(2))) float f32x2;

__device__ __forceinline__ float b2f(unsigned short u){
  union { unsigned u; float f; } v; v.u = ((unsigned)u) << 16; return v.f;
}
__device__ __forceinline__ unsigned short f2b(float f){
  union { float f; unsigned u; } v; v.f = f;
  unsigned r = v.u + 0x7FFFu + ((v.u >> 16) & 1u);
  return (unsigned short)(r >> 16);
}
// tanh-GELU via rcpf (no f32 div sequence); |err vs erf-GELU| ~3e-4
__device__ __forceinline__ float gelu_fast(float x){
  float t = 0.79788456080286536f * (x + 0.044715f * x * x * x);
  float e = __expf(2.0f * t);
  float th = 1.0f - 2.0f * __builtin_amdgcn_rcpf(e + 1.0f);
  return 0.5f * x * (1.0f + th);
}
__device__ __forceinline__ unsigned pk_bf16(float lo, float hi){
  unsigned r;
  asm("v_cvt_pk_bf16_f32 %0, %1, %2" : "=v"(r) : "v"(lo), "v"(hi));
  return r;
}
__device__ __forceinline__ void lds_barrier(){
  asm volatile("s_waitcnt lgkmcnt(0)" ::: "memory");
  __builtin_amdgcn_sched_barrier(0);
  __builtin_amdgcn_s_barrier();
  __builtin_amdgcn_sched_barrier(0);
}

// transpose-cast: dst[n][k] = (bf16)src[k][n]
__global__ __launch_bounds__(256) void transp(const float* __restrict__ src,
                                              unsigned short* __restrict__ dst,
                                              int K, int N){
  int i = blockIdx.x*256 + threadIdx.x;
  if (i < K*N){
    int n = i / K, k = i % K;
    dst[i] = f2b(src[(size_t)k*N + n]);
  }
}

// precompute bias+mask in MFMA-fragment layout:
// bw[(((slice*9 + wv)*5 + vec)*64 + lane)*8 + elem], e = vec*8+elem = ct*4+r (<36)
__global__ __launch_bounds__(256) void bias_pre(
    const float* __restrict__ btab,
    unsigned short* __restrict__ bw,
    int roll)
{
  int gid = blockIdx.x*256 + threadIdx.x;   // < 384*9*64*40
  int e    = gid % 40;
  int rem  = gid / 40;
  int lane = rem % 64;
  int rem2 = rem / 64;
  int wv   = rem2 % 9;
  int slice= rem2 / 9;
  unsigned short out = 0;
  if (e < 36){
    int ct = e >> 2, r = e & 3;
    int i = wv*16 + (lane>>4)*4 + r;
    int j = ct*16 + (lane & 15);
    int tw = slice / 6, head = slice % 6;
    int ia = i/72, ib = (i%72)/12, ic = i%12;
    int ja = j/72, jb = (j%72)/12, jc = j%12;
    int idx = (ia + 2*ja)*828 + (ib + 6*jb)*23 + (ic - jc + 11);
    float v = btab[(size_t)idx*384 + tw*6 + head];
    if (roll){
      int nz = tw >> 4, nh = tw & 15;
      int zi = nz*2+ia, hi = nh*6+ib, zj = nz*2+ja, hj = nh*6+jb;
      int ri = 3*((zi<6)?0:((zi<7)?1:2)) + ((hi<90)?0:((hi<93)?1:2));
      int rj = 3*((zj<6)?0:((zj<7)?1:2)) + ((hj<90)?0:((hj<93)?1:2));
      if (ri != rj) v -= 100.0f;
    }
    out = f2b(v);
  }
  int vec = e >> 3, elem = e & 7;
  size_t di = ((((size_t)slice*9 + wv)*5 + vec)*64 + lane)*8 + elem;
  bw[di] = out;
}

// window-partition gather (+pad +roll), fp32 -> bf16
__global__ __launch_bounds__(256) void gather_win(const float* __restrict__ x,
                                                  unsigned short* __restrict__ xw,
                                                  int roll){
  int gid = blockIdx.x*256 + threadIdx.x;
  int row = gid / 24;
  int dp  = gid % 24;
  int tok = row % 144;
  int wt  = row / 144;
  int tw  = wt & 63;
  int w   = wt >> 6;
  int nz = tw >> 4, nh = tw & 15;
  int wz = tok / 72; int rem = tok % 72; int wh = rem / 12; int ww = rem % 12;
  int z = nz*2 + wz, h = nh*6 + wh, wc = w*12 + ww;
  if (roll){ z = (z+1)&7; h = (h+3)%96; wc = (wc+6)%180; }
  int d0 = dp*8;
  u16x8 o;
  if (h < 91){
    const float* s = x + ((size_t)((z*91 + h)*180 + wc))*192 + d0;
    #pragma unroll
    for (int i=0;i<8;i++) o[i] = f2b(s[i]);
  } else {
    #pragma unroll
    for (int i=0;i<8;i++) o[i] = 0;
  }
  *(u16x8*)(xw + (size_t)row*192 + d0) = o;
}

// K=192 GEMM: C[M x N] = A[M x 192] @ Bt[N x 192]^T + bias
__global__ __launch_bounds__(512) void gemm_k192(
    const unsigned short* __restrict__ A,
    const unsigned short* __restrict__ Bt,
    const float* __restrict__ bias,
    unsigned short* __restrict__ C,
    int N)
{
  __shared__ unsigned short Bst[192][200];
  int m0 = blockIdx.x * 128;
  int n0 = blockIdx.y * 192;
  int t = threadIdx.x;
  int lane = t & 63, w = t >> 6;
  int wm = w >> 2, wn = w & 3;
  int lg = lane >> 4, lr = lane & 15;

  #pragma unroll
  for (int i=0;i<9;i++){
    int idx = t + i*512;
    int r = idx / 24, c = (idx % 24)*8;
    *(u16x8*)&Bst[r][c] = *(const u16x8*)(Bt + (size_t)(n0 + r)*192 + c);
  }
  __syncthreads();

  const unsigned short* aRow = A + (size_t)(m0 + wm*64 + lr)*192 + lg*8;

  f32x4 acc[4][3];
  #pragma unroll
  for (int a=0;a<4;a++)
    #pragma unroll
    for (int b=0;b<3;b++) acc[a][b] = (f32x4){0.f,0.f,0.f,0.f};

  bf16x8 aP[2][6];
  #pragma unroll
  for (int ks=0; ks<6; ks++) aP[0][ks] = *(const bf16x8*)(aRow + ks*32);

  #pragma unroll
  for (int rt=0; rt<4; rt++){
    if (rt < 3){
      const unsigned short* an = aRow + (size_t)(rt+1)*16*192;
      #pragma unroll
      for (int ks=0; ks<6; ks++) aP[(rt+1)&1][ks] = *(const bf16x8*)(an + ks*32);
    }
    #pragma unroll
    for (int ks=0; ks<6; ks++){
      bf16x8 b0 = *(const bf16x8*)&Bst[wn*48 +      lr][ks*32 + lg*8];
      bf16x8 b1 = *(const bf16x8*)&Bst[wn*48 + 16 + lr][ks*32 + lg*8];
      bf16x8 b2 = *(const bf16x8*)&Bst[wn*48 + 32 + lr][ks*32 + lg*8];
      bf16x8 af = aP[rt&1][ks];
      acc[rt][0] = __builtin_amdgcn_mfma_f32_16x16x32_bf16(af, b0, acc[rt][0], 0,0,0);
      acc[rt][1] = __builtin_amdgcn_mfma_f32_16x16x32_bf16(af, b1, acc[rt][1], 0,0,0);
      acc[rt][2] = __builtin_amdgcn_mfma_f32_16x16x32_bf16(af, b2, acc[rt][2], 0,0,0);
    }
  }

  #pragma unroll
  for (int rt=0; rt<4; rt++){
    #pragma unroll
    for (int fn=0; fn<3; fn++){
      int colg = n0 + wn*48 + fn*16 + lr;
      float bv = bias[colg];
      #pragma unroll
      for (int r=0;r<4;r++){
        int rowg = m0 + wm*64 + rt*16 + lg*4 + r;
        C[(size_t)rowg*N + colg] = f2b(acc[rt][fn][r] + bv);
      }
    }
  }
}

// fused windowed attention: one block per (window-pair, head). 9 waves.
// bias via fragment-layout table: 5 coalesced u16x8 loads per lane.
__global__ __launch_bounds__(576) void attn_win(
    const unsigned short* __restrict__ qkv,
    const unsigned short* __restrict__ bw,
    unsigned short* __restrict__ outp)
{
  __shared__ union {
    struct { unsigned short Qs[144][32]; unsigned short Ks[144][40]; } qk;
    unsigned short Ps[144][160];
  } U;
  __shared__ unsigned short Vst[32][160];

  int b = blockIdx.x;
  int head = b % 6;
  int wt = b / 6;
  int tw = wt & 63;
  int t = threadIdx.x;
  int lane = t & 63;
  int wv = t >> 6;
  int lg = lane >> 4, lr = lane & 15;

  {
    int tok = t >> 2, c0 = (t & 3)*8;
    size_t base = ((size_t)wt*144 + tok)*576 + head*32 + c0;
    u16x8 qv = *(const u16x8*)(qkv + base);
    u16x8 kv = *(const u16x8*)(qkv + base + 192);
    u16x8 vv = *(const u16x8*)(qkv + base + 384);
    u16x8 qs;
    #pragma unroll
    for (int i=0;i<8;i++) qs[i] = f2b(b2f(qv[i]) * 0.17677669529663687f);
    *(u16x8*)&U.qk.Qs[tok][c0] = qs;
    *(u16x8*)&U.qk.Ks[tok][c0] = kv;
    #pragma unroll
    for (int i=0;i<8;i++) Vst[c0+i][tok] = vv[i];
  }
  if (t < 512) Vst[t >> 4][144 + (t & 15)] = 0;

  u16x8 bv0, bv1, bv2, bv3, bv4;
  {
    size_t sbase = ((((size_t)(tw*6 + head))*9 + wv)*5*64 + lane)*8;
    bv0 = *(const u16x8*)(bw + sbase);
    bv1 = *(const u16x8*)(bw + sbase + 64*8);
    bv2 = *(const u16x8*)(bw + sbase + 2*64*8);
    bv3 = *(const u16x8*)(bw + sbase + 3*64*8);
    bv4 = *(const u16x8*)(bw + sbase + 4*64*8);
  }
  __syncthreads();

  float s[9][4];
  {
    bf16x8 a = *(const bf16x8*)&U.qk.Qs[wv*16 + lr][lg*8];
    #pragma unroll
    for (int ct=0; ct<9; ct++){
      bf16x8 bb = *(const bf16x8*)&U.qk.Ks[ct*16 + lr][lg*8];
      f32x4 d = {0.f,0.f,0.f,0.f};
      d = __builtin_amdgcn_mfma_f32_16x16x32_bf16(a, bb, d, 0,0,0);
      s[ct][0]=d[0]; s[ct][1]=d[1]; s[ct][2]=d[2]; s[ct][3]=d[3];
    }
  }

  #pragma unroll
  for (int ct=0; ct<9; ct++){
    #pragma unroll
    for (int r=0;r<4;r++){
      const int e = ct*4 + r;
      unsigned short bu =
        (e < 8)  ? bv0[e & 7] :
        (e < 16) ? bv1[e & 7] :
        (e < 24) ? bv2[e & 7] :
        (e < 32) ? bv3[e & 7] : bv4[e & 7];
      s[ct][r] += b2f(bu);
    }
  }

  float mx[4] = {-1e30f,-1e30f,-1e30f,-1e30f};
  #pragma unroll
  for (int ct=0; ct<9; ct++)
    #pragma unroll
    for (int r=0;r<4;r++) mx[r] = fmaxf(mx[r], s[ct][r]);
  #pragma unroll
  for (int off=1; off<16; off<<=1)
    #pragma unroll
    for (int r=0;r<4;r++) mx[r] = fmaxf(mx[r], __shfl_xor(mx[r], off));
  float sm[4] = {0.f,0.f,0.f,0.f};
  #pragma unroll
  for (int ct=0; ct<9; ct++)
    #pragma unroll
    for (int r=0;r<4;r++){ s[ct][r] = __expf(s[ct][r] - mx[r]); sm[r] += s[ct][r]; }
  #pragma unroll
  for (int off=1; off<16; off<<=1)
    #pragma unroll
    for (int r=0;r<4;r++) sm[r] += __shfl_xor(sm[r], off);
  float inv[4];
  #pragma unroll
  for (int r=0;r<4;r++) inv[r] = 1.0f / sm[r];

  lds_barrier();

  #pragma unroll
  for (int ct=0; ct<9; ct++)
    #pragma unroll
    for (int r=0;r<4;r++)
      U.Ps[wv*16 + lg*4 + r][ct*16 + lr] = f2b(s[ct][r] * inv[r]);
  #pragma unroll
  for (int r=0;r<4;r++) U.Ps[wv*16 + lg*4 + r][144 + lr] = 0;
  __syncthreads();

  #pragma unroll
  for (int ct2=0; ct2<2; ct2++){
    f32x4 o = {0.f,0.f,0.f,0.f};
    #pragma unroll
    for (int kt=0; kt<5; kt++){
      bf16x8 a  = *(const bf16x8*)&U.Ps[wv*16 + lr][kt*32 + lg*8];
      bf16x8 bb = *(const bf16x8*)&Vst[ct2*16 + lr][kt*32 + lg*8];
      o = __builtin_amdgcn_mfma_f32_16x16x32_bf16(a, bb, o, 0,0,0);
    }
    size_t rb = ((size_t)wt*144 + wv*16 + lg*4)*192 + head*32 + ct2*16 + lr;
    #pragma unroll
    for (int r=0;r<4;r++) outp[rb + (size_t)r*192] = f2b(o[r]);
  }
}

// un-window (+unroll +crop) + LN + residual
__global__ __launch_bounds__(256) void unwin_ln(
  const unsigned short* __restrict__ ywin,
  const float* __restrict__ xsrc,
  const float* __restrict__ g, const float* __restrict__ bb,
  float* __restrict__ outf, unsigned short* __restrict__ outb, int roll)
{
  int tok = blockIdx.x*4 + (threadIdx.x>>6);
  if (tok >= NTOK) return;
  int lane = threadIdx.x & 63;
  int z = tok / (91*180);
  int rem = tok % (91*180);
  int h = rem / 180, wc = rem % 180;
  int zz=z, hh=h, ww=wc;
  if (roll){ zz = (z+7)&7; hh = (h+93)%96; ww = (wc+174)%180; }
  int nz = zz>>1, wz = zz&1;
  int nh = hh/6,  wh = hh%6;
  int nw = ww/12, w2 = ww%12;
  size_t row = ((size_t)(nw*64 + nz*16 + nh))*144 + wz*72 + wh*12 + w2;
  const unsigned short* yr = ywin + row*192;
  float v[3]; float s=0.f, ss=0.f;
  #pragma unroll
  for (int i=0;i<3;i++){ v[i] = b2f(yr[lane + i*64]); s += v[i]; ss += v[i]*v[i]; }
  #pragma unroll
  for (int off=32; off>=1; off>>=1){ s += __shfl_xor(s, off); ss += __shfl_xor(ss, off); }
  float mean = s * (1.0f/192.0f);
  float var = ss * (1.0f/192.0f) - mean*mean;
  float rinv = rsqrtf(var + 1e-5f);
  size_t tb = (size_t)tok*192;
  #pragma unroll
  for (int i=0;i<3;i++){
    int d = lane + i*64;
    float o = xsrc[tb + d] + ((v[i]-mean)*rinv*g[d] + bb[d]);
    outf[tb+d] = o;
    outb[tb+d] = f2b(o);
  }
}

// fused MLP + final LN + residual: out = xmid + LN( gelu(A@W1+b1) @ W2 + b2 )
// 256 rows/block, 8 waves x 32 rows; software-pipelined:
//   gemm1(it+1) issued adjacent to gemm2(it) -> the gelu/LDS chain hides under MFMA.
// Buffering: W1s[it&1] holds chunk it; W2s[it&1] holds chunk it.
//   iter it writes W1 chunk it+2 -> W1s[it&1], W2 chunk it+1 -> W2s[(it+1)&1];
//   both one full barrier before their readers.
__global__ __launch_bounds__(512) void mlp_fused_ln(
    const unsigned short* __restrict__ A,    // [M][192] bf16
    const unsigned short* __restrict__ W1t,  // [768][192]
    const float* __restrict__ bias1,         // [768]
    const unsigned short* __restrict__ W2t,  // [192][768]
    const float* __restrict__ mbias2,        // [192]
    const float* __restrict__ xmid,          // [M][192] f32
    const float* __restrict__ lng,           // [192]
    const float* __restrict__ lnb,           // [192]
    float* __restrict__ outF,                // [M][192] f32
    int M)
{
  __shared__ unsigned short W1s[2][32][196];
  __shared__ unsigned short W2s[2][192][44];
  __shared__ unsigned short Hs[8][32][40];
  __shared__ float b1s[768];
  __shared__ float eps[576];                // [mb2 | lng | lnb]
  int m0 = blockIdx.x*256;
  int t = threadIdx.x, lane = t & 63, w = t >> 6;
  int lg = lane >> 4, lr = lane & 15;

  bf16x8 afrA[6], afrB[6];
  {
    int ra = m0 + w*32 + lr, rb = ra + 16;
    if (ra < M){
      const unsigned short* ap = A + (size_t)ra*192 + lg*8;
      #pragma unroll
      for (int ks=0; ks<6; ks++) afrA[ks] = *(const bf16x8*)(ap + ks*32);
    } else {
      #pragma unroll
      for (int ks=0; ks<6; ks++)
        #pragma unroll
        for (int j=0;j<8;j++) afrA[ks][j] = 0;
    }
    if (rb < M){
      const unsigned short* ap = A + (size_t)rb*192 + lg*8;
      #pragma unroll
      for (int ks=0; ks<6; ks++) afrB[ks] = *(const bf16x8*)(ap + ks*32);
    } else {
      #pragma unroll
      for (int ks=0; ks<6; ks++)
        #pragma unroll
        for (int j=0;j<8;j++) afrB[ks][j] = 0;
    }
  }

  b1s[t] = bias1[t];
  if (t < 256) b1s[512 + t] = bias1[512 + t];
  if (t < 192){ eps[t] = mbias2[t]; eps[192 + t] = lng[t]; eps[384 + t] = lnb[t]; }

  int i1r[2], i1c[2], i2r[2], i2c[2];
  #pragma unroll
  for (int i=0;i<2;i++){
    int idx = t + i*512;
    i1r[i] = idx/24; i1c[i] = (idx%24)*8;
    i2r[i] = idx/4;  i2c[i] = (idx&3)*8;
  }
  bool g2nd = (t + 512) < 768;

  // prologue: W1 chunk0 -> W1s[0], W1 chunk1 -> W1s[1], W2 chunk0 -> W2s[0]
  {
    *(u16x8*)&W1s[0][i1r[0]][i1c[0]] = *(const u16x8*)(W1t + (size_t)i1r[0]*192 + i1c[0]);
    *(u16x8*)&W1s[1][i1r[0]][i1c[0]] = *(const u16x8*)(W1t + (size_t)(32 + i1r[0])*192 + i1c[0]);
    *(u16x8*)&W2s[0][i2r[0]][i2c[0]] = *(const u16x8*)(W2t + (size_t)i2r[0]*768 + i2c[0]);
    if (g2nd){
      *(u16x8*)&W1s[0][i1r[1]][i1c[1]] = *(const u16x8*)(W1t + (size_t)i1r[1]*192 + i1c[1]);
      *(u16x8*)&W1s[1][i1r[1]][i1c[1]] = *(const u16x8*)(W1t + (size_t)(32 + i1r[1])*192 + i1c[1]);
      *(u16x8*)&W2s[0][i2r[1]][i2c[1]] = *(const u16x8*)(W2t + (size_t)i2r[1]*768 + i2c[1]);
    }
  }
  lds_barrier();

  // prefetch regs: w1r = W1 chunk2 (write at it=0), w2r = W2 chunk1 (write at it=0)
  u16x8 w1r[2], w2r[2];
  w1r[0] = *(const u16x8*)(W1t + (size_t)(64 + i1r[0])*192 + i1c[0]);
  w2r[0] = *(const u16x8*)(W2t + (size_t)i2r[0]*768 + 32 + i2c[0]);
  if (g2nd){
    w1r[1] = *(const u16x8*)(W1t + (size_t)(64 + i1r[1])*192 + i1c[1]);
    w2r[1] = *(const u16x8*)(W2t + (size_t)i2r[1]*768 + 32 + i2c[1]);
  }

  // h = gemm1(chunk 0) from W1s[0]
  f32x4 h0a = (f32x4){0.f,0.f,0.f,0.f}, h1a = h0a, h0b = h0a, h1b = h0a;
  #pragma unroll
  for (int ks=0; ks<6; ks++){
    bf16x8 b0  = *(const bf16x8*)&W1s[0][2*lr    ][ks*32 + lg*8];
    bf16x8 b1f = *(const bf16x8*)&W1s[0][2*lr + 1][ks*32 + lg*8];
    h0a = __builtin_amdgcn_mfma_f32_16x16x32_bf16(afrA[ks], b0,  h0a, 0,0,0);
    h1a = __builtin_amdgcn_mfma_f32_16x16x32_bf16(afrA[ks], b1f, h1a, 0,0,0);
    h0b = __builtin_amdgcn_mfma_f32_16x16x32_bf16(afrB[ks], b0,  h0b, 0,0,0);
    h1b = __builtin_amdgcn_mfma_f32_16x16x32_bf16(afrB[ks], b1f, h1b, 0,0,0);
  }
  lds_barrier();   // all gemm1(0) reads of W1s[0] done before it=0 overwrites it

  f32x4 accA[12], accB[12];
  #pragma unroll
  for (int i=0;i<12;i++){ accA[i] = (f32x4){0.f,0.f,0.f,0.f}; accB[i] = (f32x4){0.f,0.f,0.f,0.f}; }

  for (int it=0; it<24; ++it){
    int cur = it & 1, nxt = cur ^ 1;

    // A: top writes (regs hold W1 chunk it+2, W2 chunk it+1)
    if (it < 22){
      *(u16x8*)&W1s[cur][i1r[0]][i1c[0]] = w1r[0];
      if (g2nd) *(u16x8*)&W1s[cur][i1r[1]][i1c[1]] = w1r[1];
    }
    if (it < 23){
      *(u16x8*)&W2s[nxt][i2r[0]][i2c[0]] = w2r[0];
      if (g2nd) *(u16x8*)&W2s[nxt][i2r[1]][i2c[1]] = w2r[1];
    }
    // B: issue next loads (W1 chunk it+3, W2 chunk it+2)
    if (it < 21){
      w1r[0] = *(const u16x8*)(W1t + (size_t)((it+3)*32 + i1r[0])*192 + i1c[0]);
      if (g2nd) w1r[1] = *(const u16x8*)(W1t + (size_t)((it+3)*32 + i1r[1])*192 + i1c[1]);
    }
    if (it < 22){
      w2r[0] = *(const u16x8*)(W2t + (size_t)i2r[0]*768 + (it+2)*32 + i2c[0]);
      if (g2nd) w2r[1] = *(const u16x8*)(W2t + (size_t)i2r[1]*768 + (it+2)*32 + i2c[1]);
    }

    // C: gelu(h(it)) -> Hs -> pa reads
    int hc = it*32;
    float bb0 = b1s[hc + 2*lr];
    float bb1 = b1s[hc + 2*lr + 1];
    #pragma unroll
    for (int r=0;r<4;r++){
      *(unsigned*)&Hs[w][lg*4 + r][2*lr] =
          pk_bf16(gelu_fast(h0a[r] + bb0), gelu_fast(h1a[r] + bb1));
      *(unsigned*)&Hs[w][16 + lg*4 + r][2*lr] =
          pk_bf16(gelu_fast(h0b[r] + bb0), gelu_fast(h1b[r] + bb1));
    }
    bf16x8 paA = *(const bf16x8*)&Hs[w][lr][lg*8];
    bf16x8 paB = *(const bf16x8*)&Hs[w][16 + lr][lg*8];

    // D: gemm1(it+1) from W1s[nxt] (independent of C's chain)
    f32x4 hn0a = (f32x4){0.f,0.f,0.f,0.f}, hn1a = hn0a, hn0b = hn0a, hn1b = hn0a;
    if (it < 23){
      #pragma unroll
      for (int ks=0; ks<6; ks++){
        bf16x8 b0  = *(const bf16x8*)&W1s[nxt][2*lr    ][ks*32 + lg*8];
        bf16x8 b1f = *(const bf16x8*)&W1s[nxt][2*lr + 1][ks*32 + lg*8];
        hn0a = __builtin_amdgcn_mfma_f32_16x16x32_bf16(afrA[ks], b0,  hn0a, 0,0,0);
        hn1a = __builtin_amdgcn_mfma_f32_16x16x32_bf16(afrA[ks], b1f, hn1a, 0,0,0);
        hn0b = __builtin_amdgcn_mfma_f32_16x16x32_bf16(afrB[ks], b0,  hn0b, 0,0,0);
        hn1b = __builtin_amdgcn_mfma_f32_16x16x32_bf16(afrB[ks], b1f, hn1b, 0,0,0);
      }
    }

    // E: gemm2(it) from W2s[cur]
    #pragma unroll
    for (int f=0; f<6; f++){
      bf16x8 c0 = *(const bf16x8*)&W2s[cur][f*32 + 2*lr    ][lg*8];
      bf16x8 c1 = *(const bf16x8*)&W2s[cur][f*32 + 2*lr + 1][lg*8];
      accA[2*f]   = __builtin_amdgcn_mfma_f32_16x16x32_bf16(paA, c0, accA[2*f],   0,0,0);
      accA[2*f+1] = __builtin_amdgcn_mfma_f32_16x16x32_bf16(paA, c1, accA[2*f+1], 0,0,0);
      accB[2*f]   = __builtin_amdgcn_mfma_f32_16x16x32_bf16(paB, c0, accB[2*f],   0,0,0);
      accB[2*f+1] = __builtin_amdgcn_mfma_f32_16x16x32_bf16(paB, c1, accB[2*f+1], 0,0,0);
    }

    h0a = hn0a; h1a = hn1a; h0b = hn0b; h1b = hn1b;
    lds_barrier();
  }

  #pragma unroll
  for (int gsel=0; gsel<2; gsel++){
    f32x4* acc = gsel ? accB : accA;
    #pragma unroll
    for (int r=0;r<4;r++){
      int row = m0 + w*32 + gsel*16 + lg*4 + r;
      float s = 0.f, ss = 0.f;
      #pragma unroll
      for (int f=0; f<6; f++){
        float v0 = acc[2*f][r]   + eps[f*32 + 2*lr];
        float v1 = acc[2*f+1][r] + eps[f*32 + 2*lr + 1];
        s += v0 + v1; ss += v0*v0 + v1*v1;
      }
      #pragma unroll
      for (int off=1; off<16; off<<=1){ s += __shfl_xor(s, off); ss += __shfl_xor(ss, off); }
      float mean = s * (1.0f/192.0f);
      float var  = ss * (1.0f/192.0f) - mean*mean;
      float rinv = rsqrtf(var + 1e-5f);
      if (row < M){
        size_t base = (size_t)row*192;
        #pragma unroll
        for (int f=0; f<6; f++){
          int c0 = f*32 + 2*lr;
          float v0 = acc[2*f][r]   + eps[c0];
          float v1 = acc[2*f+1][r] + eps[c0 + 1];
          f32x2 xm = *(const f32x2*)&xmid[base + c0];
          f32x2 o;
          o[0] = xm[0] + (v0 - mean)*rinv*eps[192 + c0]     + eps[384 + c0];
          o[1] = xm[1] + (v1 - mean)*rinv*eps[192 + c0 + 1] + eps[384 + c0 + 1];
          *(f32x2*)&outF[base + c0] = o;
        }
      }
    }
  }
}

extern "C" void kernel_launch(void* const* d_in, const int* in_sizes, int n_in,
                              void* d_out, int out_size, void* d_ws, size_t ws_size,
                              hipStream_t stream)
{
  const float* x_in    = (const float*)d_in[0];
  const float* qkvw    = (const float*)d_in[1];
  const float* qkvbias = (const float*)d_in[2];
  const float* projw   = (const float*)d_in[3];
  const float* projbias= (const float*)d_in[4];
  const float* btab    = (const float*)d_in[5];
  const float* n1g = (const float*)d_in[6];
  const float* n1b = (const float*)d_in[7];
  const float* n2g = (const float*)d_in[8];
  const float* n2b = (const float*)d_in[9];
  const float* w1  = (const float*)d_in[10];
  const float* b1  = (const float*)d_in[11];
  const float* w2  = (const float*)d_in[12];
  const float* b2  = (const float*)d_in[13];
  float* outp = (float*)d_out;

  const size_t REG_A = (size_t)NTOKW*192;
  const size_t REG_B = (size_t)NTOKW*576;
  const size_t W_QT  = (size_t)2*576*192;
  const size_t W_PT  = (size_t)2*192*192;
  const size_t W_1T  = (size_t)2*768*192;
  const size_t W_2T  = (size_t)2*192*768;
  const size_t TOT_SH = REG_A + REG_B + W_QT + W_PT + W_1T + W_2T;
  const size_t NEEDED = TOT_SH*2 + (size_t)NTOK*192*4;
  if (ws_size < NEEDED) return;

  unsigned short* ws16 = (unsigned short*)d_ws;
  size_t off = 0;
  unsigned short* regA = ws16 + off; off += REG_A;   // xw / attn-out / xmidb
  unsigned short* regB = ws16 + off; off += REG_B;   // qkv-out / ywin
  unsigned short* wqt  = ws16 + off; off += W_QT;
  unsigned short* wpt  = ws16 + off; off += W_PT;
  unsigned short* w1t  = ws16 + off; off += W_1T;
  unsigned short* w2t  = ws16 + off; off += W_2T;
  float* xmidf = (float*)(ws16 + off);
  unsigned short* bw = (unsigned short*)xmidf;   // alias: dead before unwin_ln writes xmidf

  for (int dep=0; dep<2; dep++){
    transp<<<(192*576+255)/256,256,0,stream>>>(qkvw + (size_t)dep*192*576,
                                               wqt + (size_t)dep*576*192, 192, 576);
    transp<<<(192*192+255)/256,256,0,stream>>>(projw + (size_t)dep*192*192,
                                               wpt + (size_t)dep*192*192, 192, 192);
    transp<<<(192*768+255)/256,256,0,stream>>>(w1 + (size_t)dep*192*768,
                                               w1t + (size_t)dep*768*192, 192, 768);
    transp<<<(768*192+255)/256,256,0,stream>>>(w2 + (size_t)dep*768*192,
                                               w2t + (size_t)dep*192*768, 768, 192);
  }

  for (int dep=0; dep<2; dep++){
    int roll = dep;
    const float* xs = (dep==0) ? x_in : outp;
    float* xout = outp;

    gather_win<<<NTOKW*24/256, 256, 0, stream>>>(xs, regA, roll);

    dim3 g1(NTOKW/128, 3);     // N=576
    gemm_k192<<<g1, 512, 0, stream>>>(regA, wqt + (size_t)dep*576*192,
                                      qkvbias + dep*576, regB, 576);

    bias_pre<<<(384*9*64*40)/256, 256, 0, stream>>>(btab + (size_t)dep*3312*384, bw, roll);

    attn_win<<<960*6, 576, 0, stream>>>(regB, bw, regA);

    dim3 g2(NTOKW/128, 1);     // N=192
    gemm_k192<<<g2, 512, 0, stream>>>(regA, wpt + (size_t)dep*192*192,
                                      projbias + dep*192, regB, 192);

    unwin_ln<<<NTOK/4, 256, 0, stream>>>(regB, xs, n1g + dep*192, n1b + dep*192,
                                         xmidf, regA, roll);

    mlp_fused_ln<<<(NTOK+255)/256, 512, 0, stream>>>(
        regA, w1t + (size_t)dep*768*192, b1 + dep*768,
        w2t + (size_t)dep*192*768, b2 + dep*192,
        xmidf, n2g + dep*192, n2b + dep*192, xout, NTOK);
  }
}